// Round 1
// baseline (2092.307 us; speedup 1.0000x reference)
//
#include <hip/hip_runtime.h>
#include <cstdint>
#include <cstddef>

#define EPS_V 1e-5f

// broadcast lane l's value of v to all lanes (l wave-uniform / compile-time)
__device__ __forceinline__ float rlane(float v, int l) {
    return __int_as_float(__builtin_amdgcn_readlane(__float_as_int(v), l));
}

// ---------------- mask dtype detection + canonical packing ----------------
// If masks arrive as byte-bools, int32 reads of the buffer mix 4 bools/word ->
// values >= 256 appear with certainty at ~50% density. If int32 0/1, all words
// are 0 or 1. flag=1 -> byte storage, flag=0 -> int32 storage.
__global__ void k_detect(const unsigned int* __restrict__ w, int nwords,
                         int* __restrict__ flag) {
    unsigned loc = 0;
    for (int i = threadIdx.x; i < nwords; i += blockDim.x)
        if (w[i] > 1u) loc = 1u;
    if (loc) atomicOr(flag, 1);
}

__global__ void k_pack(const void* __restrict__ mask, int M,
                       const int* __restrict__ flag, unsigned char* __restrict__ pm) {
    int r = blockIdx.x * blockDim.x + threadIdx.x;
    if (r >= M) return;
    unsigned byte = 0;
    if (*flag) {
        const unsigned char* mb = (const unsigned char*)mask;
        #pragma unroll
        for (int k = 0; k < 8; k++) byte |= (mb[r * 8 + k] ? 1u : 0u) << k;
    } else {
        const int* mi = (const int*)mask;
        #pragma unroll
        for (int k = 0; k < 8; k++) byte |= (mi[r * 8 + k] ? 1u : 0u) << k;
    }
    pm[r] = (unsigned char)byte;
}

// ---------------- layer 1: sparse conv, Cin=32 Cout=64, W [8][32][64] -------
// Full W (64KB) in LDS. One wave handles 2 rows; lane = output channel.
__global__ __launch_bounds__(256)
void k_sconv1(const float* __restrict__ xin, const float* __restrict__ W,
              const int* __restrict__ idx, const unsigned char* __restrict__ pm,
              float* __restrict__ out, int M) {
    __shared__ float Wl[8 * 32 * 64];
    {
        const float4* src = (const float4*)W;
        float4* dst = (float4*)Wl;
        for (int i = threadIdx.x; i < 4096; i += 256) dst[i] = src[i];
    }
    __syncthreads();
    const int wid = threadIdx.x >> 6, lane = threadIdx.x & 63;
    const int li = lane & 31;
    const int wavesTotal = gridDim.x * 4;
    for (int pid = blockIdx.x * 4 + wid; pid * 2 < M; pid += wavesTotal) {
        int r0 = pid * 2, r1 = r0 + 1;
        bool h1 = r1 < M;
        unsigned m0 = pm[r0];
        unsigned m1 = h1 ? (unsigned)pm[r1] : 0u;
        float acc0 = 0.f, acc1 = 0.f;
        #pragma unroll
        for (int k = 0; k < 8; k++) {
            unsigned b0 = (m0 >> k) & 1u, b1 = (m1 >> k) & 1u;
            if (!(b0 | b1)) continue;              // wave-uniform skip
            float v0 = 0.f, v1 = 0.f;
            if (b0) v0 = xin[(size_t)idx[r0 * 8 + k] * 32 + li];
            if (b1) v1 = xin[(size_t)idx[r1 * 8 + k] * 32 + li];
            #pragma unroll
            for (int i = 0; i < 32; i++) {
                float wv = Wl[(k * 32 + i) * 64 + lane];   // stride-1: conflict-free
                acc0 = fmaf(rlane(v0, i), wv, acc0);
                acc1 = fmaf(rlane(v1, i), wv, acc1);
            }
        }
        out[(size_t)r0 * 64 + lane] = acc0;
        if (h1) out[(size_t)r1 * 64 + lane] = acc1;
    }
}

// ---------------- layer 2: sparse conv, Cin=64 Cout=128, W [8][64][128] -----
// W is 256KB -> stage one 32KB tap at a time; accumulators persist in regs.
// Block covers 16 rows (4 waves x 4 rows). Grid = N2/16 exactly.
__global__ __launch_bounds__(256)
void k_sconv2(const float* __restrict__ xin, const float* __restrict__ W,
              const int* __restrict__ idx, const unsigned char* __restrict__ pm,
              float* __restrict__ out, int M) {
    __shared__ float Wl[64 * 128];
    const int wid = threadIdx.x >> 6, lane = threadIdx.x & 63;
    const int rowBase = blockIdx.x * 16 + wid * 4;
    float acc[4][2];
    #pragma unroll
    for (int r = 0; r < 4; r++) acc[r][0] = acc[r][1] = 0.f;
    unsigned mrow[4];
    #pragma unroll
    for (int r = 0; r < 4; r++) {
        int row = rowBase + r;
        mrow[r] = (row < M) ? (unsigned)pm[row] : 0u;
    }
    for (int k = 0; k < 8; k++) {
        __syncthreads();
        const float4* src = (const float4*)(W + k * 64 * 128);
        float4* dst = (float4*)Wl;
        for (int i = threadIdx.x; i < 2048; i += 256) dst[i] = src[i];
        __syncthreads();
        #pragma unroll
        for (int r = 0; r < 4; r++) {
            if (!((mrow[r] >> k) & 1u)) continue;  // wave-uniform
            int row = rowBase + r;
            float v = xin[(size_t)idx[row * 8 + k] * 64 + lane];
            float a0 = acc[r][0], a1 = acc[r][1];
            #pragma unroll
            for (int i = 0; i < 64; i++) {
                float a = rlane(v, i);
                a0 = fmaf(a, Wl[i * 128 + lane], a0);
                a1 = fmaf(a, Wl[i * 128 + 64 + lane], a1);
            }
            acc[r][0] = a0; acc[r][1] = a1;
        }
    }
    #pragma unroll
    for (int r = 0; r < 4; r++) {
        int row = rowBase + r;
        if (row < M) {
            out[(size_t)row * 128 + lane]      = acc[r][0];
            out[(size_t)row * 128 + 64 + lane] = acc[r][1];
        }
    }
}

// ---------------- layer 3: tconv, Cin=128 Cout=64, W [8][128][64] -----------
// W is 256KB -> loop octants; stage W[o] (32KB); each pass computes rows whose
// off==o fully and writes them. Row's octant is wave-uniform.
__global__ __launch_bounds__(256)
void k_tconv_d2(const float* __restrict__ xin, const float* __restrict__ W,
                const int* __restrict__ par, const int* __restrict__ off,
                float* __restrict__ out, int M) {
    __shared__ float Wl[128 * 64];
    const int wid = threadIdx.x >> 6, lane = threadIdx.x & 63;
    for (int o = 0; o < 8; o++) {
        __syncthreads();
        const float4* src = (const float4*)(W + o * 128 * 64);
        float4* dst = (float4*)Wl;
        for (int i = threadIdx.x; i < 2048; i += 256) dst[i] = src[i];
        __syncthreads();
        for (int chunk = blockIdx.x; chunk * 64 < M; chunk += gridDim.x) {
            int rbase = chunk * 64 + wid * 16;
            for (int r = 0; r < 16; r++) {
                int row = rbase + r;
                if (row >= M) break;
                if (off[row] != o) continue;       // wave-uniform
                const float* fp = xin + (size_t)par[row] * 128;
                float v0 = fp[lane], v1 = fp[64 + lane];
                float a0 = 0.f, a1 = 0.f;          // 2 chains for FMA-latency ILP
                #pragma unroll
                for (int i = 0; i < 64; i++) {
                    a0 = fmaf(rlane(v0, i), Wl[i * 64 + lane], a0);
                    a1 = fmaf(rlane(v1, i), Wl[(64 + i) * 64 + lane], a1);
                }
                out[(size_t)row * 64 + lane] = a0 + a1;
            }
        }
    }
}

// ---------------- layer 4: tconv, Cin=64 Cout=32, W [8][64][32] -------------
// Full W (64KB) in LDS. Wave = 2 rows x 32 outputs (half-wave per row).
__global__ __launch_bounds__(256)
void k_tconv_d1(const float* __restrict__ xin, const float* __restrict__ W,
                const int* __restrict__ par, const int* __restrict__ off,
                float* __restrict__ out, int M) {
    __shared__ float Wl[8 * 64 * 32];
    {
        const float4* src = (const float4*)W;
        float4* dst = (float4*)Wl;
        for (int i = threadIdx.x; i < 4096; i += 256) dst[i] = src[i];
    }
    __syncthreads();
    const int wid = threadIdx.x >> 6, lane = threadIdx.x & 63;
    const int half = lane >> 5, lo = lane & 31;
    const int wavesTotal = gridDim.x * 4;
    for (int pid = blockIdx.x * 4 + wid; pid * 2 < M; pid += wavesTotal) {
        int r0 = pid * 2, r1 = r0 + 1;
        bool h1 = r1 < M;
        if (!h1) r1 = r0;
        const float* f0 = xin + (size_t)par[r0] * 64;
        const float* f1 = xin + (size_t)par[r1] * 64;
        float v0 = f0[lane], v1 = f1[lane];        // each full row across 64 lanes
        int wb = (half ? off[r1] : off[r0]) * (64 * 32) + lo;
        float a0 = 0.f, a1 = 0.f;
        #pragma unroll
        for (int i = 0; i < 64; i += 2) {
            float sa = half ? rlane(v1, i)     : rlane(v0, i);
            float sb = half ? rlane(v1, i + 1) : rlane(v0, i + 1);
            a0 = fmaf(sa, Wl[wb + i * 32], a0);
            a1 = fmaf(sb, Wl[wb + (i + 1) * 32], a1);
        }
        // lanes 0-31 -> row r0, lanes 32-63 -> row r1 (contiguous 256B store)
        if (h1 || half == 0) out[(size_t)r0 * 32 + lane] = a0 + a1;
    }
}

// ---------------- per-channel sum / sumsq ----------------
// st layout per layer: [0..C) sum, [128..128+C) sumsq
template <int C>
__global__ __launch_bounds__(256)
void k_stats(const float* __restrict__ f, int M, float* __restrict__ st) {
    constexpr int RPB = 256 / C;
    __shared__ float ls[2 * C];
    if (threadIdx.x < 2 * C) ls[threadIdx.x] = 0.f;
    __syncthreads();
    const int c = threadIdx.x % C;
    const int rsub = threadIdx.x / C;
    float s = 0.f, q = 0.f;
    for (int row = blockIdx.x * RPB + rsub; row < M; row += gridDim.x * RPB) {
        float v = f[(size_t)row * C + c];
        s += v;
        q = fmaf(v, v, q);
    }
    atomicAdd(&ls[c], s);
    atomicAdd(&ls[C + c], q);
    __syncthreads();
    if (threadIdx.x < C) {
        atomicAdd(&st[threadIdx.x], ls[threadIdx.x]);
        atomicAdd(&st[128 + threadIdx.x], ls[C + threadIdx.x]);
    }
}

// ---------------- in-place instance norm ----------------
template <int C>
__global__ __launch_bounds__(256)
void k_norm(float* __restrict__ f, int M, const float* __restrict__ st,
            const float* __restrict__ g, const float* __restrict__ b) {
    __shared__ float sc[C], sh[C];
    if (threadIdx.x < C) {
        int c = threadIdx.x;
        float invM = 1.0f / (float)M;
        float mu = st[c] * invM;
        float var = fmaf(st[128 + c], invM, -mu * mu);   // biased var
        float s = rsqrtf(var + EPS_V) * g[c];
        sc[c] = s;
        sh[c] = fmaf(-mu, s, b[c]);
    }
    __syncthreads();
    const int total = M * (C / 4);
    const int cq = C / 4;
    float4* p = (float4*)f;
    for (int i = blockIdx.x * blockDim.x + threadIdx.x; i < total;
         i += gridDim.x * blockDim.x) {
        float4 v = p[i];
        int c0 = (i % cq) * 4;
        v.x = fmaf(v.x, sc[c0 + 0], sh[c0 + 0]);
        v.y = fmaf(v.y, sc[c0 + 1], sh[c0 + 1]);
        v.z = fmaf(v.z, sc[c0 + 2], sh[c0 + 2]);
        v.w = fmaf(v.w, sc[c0 + 3], sh[c0 + 3]);
        p[i] = v;
    }
}

extern "C" void kernel_launch(void* const* d_in, const int* in_sizes, int n_in,
                              void* d_out, int out_size, void* d_ws, size_t ws_size,
                              hipStream_t stream) {
    const float* x   = (const float*)d_in[0];
    const float* W1  = (const float*)d_in[1];   // [8][32][64]
    const float* W2  = (const float*)d_in[2];   // [8][64][128]
    const float* W3  = (const float*)d_in[3];   // [8][128][64]
    const float* W4  = (const float*)d_in[4];   // [8][64][32]
    const float* g1  = (const float*)d_in[5];
    const float* b1  = (const float*)d_in[6];
    const float* g2  = (const float*)d_in[7];
    const float* b2  = (const float*)d_in[8];
    const float* g3  = (const float*)d_in[9];
    const float* b3  = (const float*)d_in[10];
    const float* g4  = (const float*)d_in[11];
    const float* b4  = (const float*)d_in[12];
    const int*  idx1 = (const int*)d_in[13];
    const void* msk1 = d_in[14];
    const int*  idx2 = (const int*)d_in[15];
    const void* msk2 = d_in[16];
    const int*  par2 = (const int*)d_in[17];
    const int*  off2 = (const int*)d_in[18];
    const int*  par1 = (const int*)d_in[19];
    const int*  off1 = (const int*)d_in[20];

    const int N1 = in_sizes[17];        // par_d2 length
    const int N0 = in_sizes[19];        // par_d1 length
    const int N2 = in_sizes[15] / 8;    // idx_up2 rows

    // output slots, in reference return order
    float* outp = (float*)d_out;
    float* sA = outp;                          // x_down2 [N0,32]
    float* sB = sA + (size_t)N0 * 32;          // x_down1 [N1,64]
    float* sC = sB + (size_t)N1 * 64;          // x_up2   [N2,128]
    float* sD = sC + (size_t)N2 * 128;         // x_up1   [N1,64]

    // workspace: [0,16) flag, [16,16+4096) stats (4 layers x 256 floats), masks
    char* w = (char*)d_ws;
    int*   flag = (int*)w;
    float* st   = (float*)(w + 16);
    float* st1 = st, *st2 = st + 256, *st3 = st + 512, *st4 = st + 768;
    unsigned char* pm1 = (unsigned char*)(w + 16 + 4096);
    unsigned char* pm2 = pm1 + (((size_t)N1 + 255) & ~(size_t)255);

    hipMemsetAsync(d_ws, 0, 16 + 4096, stream);

    int nwords = N1 * 8 / 4; if (nwords > 4096) nwords = 4096;
    k_detect<<<1, 256, 0, stream>>>((const unsigned int*)msk1, nwords, flag);
    k_pack<<<(N1 + 255) / 256, 256, 0, stream>>>(msk1, N1, flag, pm1);
    k_pack<<<(N2 + 255) / 256, 256, 0, stream>>>(msk2, N2, flag, pm2);

    // layer 1 -> x_up1 (slot D)
    k_sconv1<<<1024, 256, 0, stream>>>(x, W1, idx1, pm1, sD, N1);
    k_stats<64><<<512, 256, 0, stream>>>(sD, N1, st1);
    k_norm<64><<<1024, 256, 0, stream>>>(sD, N1, st1, g1, b1);

    // layer 2 -> x_up2 (slot C)
    k_sconv2<<<(N2 + 15) / 16, 256, 0, stream>>>(sD, W2, idx2, pm2, sC, N2);
    k_stats<128><<<512, 256, 0, stream>>>(sC, N2, st2);
    k_norm<128><<<512, 256, 0, stream>>>(sC, N2, st2, g2, b2);

    // layer 3 -> x_down1 (slot B)
    k_tconv_d2<<<1024, 256, 0, stream>>>(sC, W3, par2, off2, sB, N1);
    k_stats<64><<<512, 256, 0, stream>>>(sB, N1, st3);
    k_norm<64><<<1024, 256, 0, stream>>>(sB, N1, st3, g3, b3);

    // layer 4 -> x_down2 (slot A)
    k_tconv_d1<<<1024, 256, 0, stream>>>(sB, W4, par1, off1, sA, N0);
    k_stats<32><<<512, 256, 0, stream>>>(sA, N0, st4);
    k_norm<32><<<1024, 256, 0, stream>>>(sA, N0, st4, g4, b4);
}

// Round 2
// 709.151 us; speedup vs baseline: 2.9504x; 2.9504x over previous
//
#include <hip/hip_runtime.h>
#include <cstdint>
#include <cstddef>

#define EPS_V 1e-5f

typedef __attribute__((ext_vector_type(8))) short bf16x8;
typedef __attribute__((ext_vector_type(4))) float f32x4;

__device__ __forceinline__ unsigned short f2b(float f) {
    unsigned u = __float_as_uint(f);
    u = (u + 0x7FFFu + ((u >> 16) & 1u)) >> 16;      // RNE
    return (unsigned short)u;
}

__device__ __forceinline__ bf16x8 cvt8(float4 a, float4 b) {
    bf16x8 r;
    r[0] = (short)f2b(a.x); r[1] = (short)f2b(a.y);
    r[2] = (short)f2b(a.z); r[3] = (short)f2b(a.w);
    r[4] = (short)f2b(b.x); r[5] = (short)f2b(b.y);
    r[6] = (short)f2b(b.z); r[7] = (short)f2b(b.w);
    return r;
}

// ---------------- mask dtype detection + packing (unchanged, verified R1) ---
__global__ void k_detect(const unsigned int* __restrict__ w, int nwords,
                         int* __restrict__ flag) {
    unsigned loc = 0;
    for (int i = threadIdx.x; i < nwords; i += blockDim.x)
        if (w[i] > 1u) loc = 1u;
    if (loc) atomicOr(flag, 1);
}

__global__ void k_pack(const void* __restrict__ mask, int M,
                       const int* __restrict__ flag, unsigned char* __restrict__ pm) {
    int r = blockIdx.x * blockDim.x + threadIdx.x;
    if (r >= M) return;
    unsigned byte = 0;
    if (*flag) {
        const unsigned char* mb = (const unsigned char*)mask;
        #pragma unroll
        for (int k = 0; k < 8; k++) byte |= (mb[r * 8 + k] ? 1u : 0u) << k;
    } else {
        const int* mi = (const int*)mask;
        #pragma unroll
        for (int k = 0; k < 8; k++) byte |= (mi[r * 8 + k] ? 1u : 0u) << k;
    }
    pm[r] = (unsigned char)byte;
}

// ---------------- weight shuffle: fp32 [t][k][c] -> bf16 B-frag layout ------
// Wshuf[((t*KB+kb)*NB+nb)*64 + L][j] = bf16( W[t][kb*32 + (L>>4)*8 + j][nb*16 + (L&15)] )
__global__ void k_wshuf(const float* __restrict__ W, int taps, int Cin, int Cout,
                        unsigned short* __restrict__ dst) {
    int KB = Cin >> 5, NB = Cout >> 4;
    int total = taps * KB * NB * 64;
    for (int g = blockIdx.x * blockDim.x + threadIdx.x; g < total;
         g += gridDim.x * blockDim.x) {
        int L = g & 63;
        int rest = g >> 6;
        int nb = rest % NB; rest /= NB;
        int kb = rest % KB; int t = rest / KB;
        int q = L >> 4, col = nb * 16 + (L & 15);
        const float* src = W + ((size_t)t * Cin + kb * 32 + q * 8) * Cout + col;
        unsigned short* d = dst + (size_t)g * 8;
        #pragma unroll
        for (int j = 0; j < 8; j++) d[j] = f2b(src[(size_t)j * Cout]);
    }
}

// ---------------- conv1: sparse, Cin=32 (KB=1), Cout=64 (NB=4), 8 taps ------
__global__ __launch_bounds__(256)
void k_conv1(const float* __restrict__ xin, const unsigned short* __restrict__ Wsh,
             const int* __restrict__ idx, const unsigned char* __restrict__ pm,
             float* __restrict__ out, float* __restrict__ st, int M) {
    __shared__ unsigned short Wl[8 * 4 * 64 * 8];   // 32KB
    __shared__ float ls[2 * 64];
    {
        const int4* s = (const int4*)Wsh; int4* d = (int4*)Wl;
        for (int i = threadIdx.x; i < 2048; i += 256) d[i] = s[i];
    }
    if (threadIdx.x < 128) ls[threadIdx.x] = 0.f;
    __syncthreads();
    const int lane = threadIdx.x & 63, wid = threadIdx.x >> 6;
    const int q = lane >> 4, li = lane & 15;
    int tile = blockIdx.x * 4 + wid;
    float sum[4] = {0, 0, 0, 0}, sq[4] = {0, 0, 0, 0};
    if (tile * 16 < M) {
        int rowA = tile * 16 + li;
        unsigned m = pm[rowA];
        const int* ip = idx + (size_t)rowA * 8;
        f32x4 acc[4];
        #pragma unroll
        for (int nb = 0; nb < 4; nb++) acc[nb] = (f32x4)0.f;
        #pragma unroll
        for (int t = 0; t < 8; t++) {
            float4 f0 = {0, 0, 0, 0}, f1 = {0, 0, 0, 0};
            if ((m >> t) & 1u) {
                const float4* p = (const float4*)(xin + (size_t)ip[t] * 32 + q * 8);
                f0 = p[0]; f1 = p[1];
            }
            bf16x8 a = cvt8(f0, f1);
            #pragma unroll
            for (int nb = 0; nb < 4; nb++) {
                bf16x8 b = *(const bf16x8*)&Wl[((t * 4 + nb) * 64 + lane) * 8];
                acc[nb] = __builtin_amdgcn_mfma_f32_16x16x32_bf16(a, b, acc[nb], 0, 0, 0);
            }
        }
        int rowD = tile * 16 + q * 4;
        #pragma unroll
        for (int nb = 0; nb < 4; nb++)
            #pragma unroll
            for (int r = 0; r < 4; r++) {
                float v = acc[nb][r];
                out[(size_t)(rowD + r) * 64 + nb * 16 + li] = v;
                sum[nb] += v; sq[nb] = fmaf(v, v, sq[nb]);
            }
    }
    #pragma unroll
    for (int nb = 0; nb < 4; nb++) {
        int c = nb * 16 + li;
        atomicAdd(&ls[c], sum[nb]); atomicAdd(&ls[64 + c], sq[nb]);
    }
    __syncthreads();
    if (threadIdx.x < 64) {
        atomicAdd(&st[threadIdx.x], ls[threadIdx.x]);
        atomicAdd(&st[128 + threadIdx.x], ls[64 + threadIdx.x]);
    }
}

// ---------------- conv2: sparse, Cin=64 (KB=2), Cout=128 (NB=8), 8 taps -----
// Tap-staged weights (16KB/tap). Grid exactly M/16/4 blocks (tile per wave).
__global__ __launch_bounds__(256)
void k_conv2(const float* __restrict__ xin, const unsigned short* __restrict__ Wsh,
             const int* __restrict__ idx, const unsigned char* __restrict__ pm,
             float* __restrict__ out, float* __restrict__ st, int M) {
    __shared__ unsigned short Wl[2 * 8 * 64 * 8];   // 16KB, one tap
    __shared__ float ls[2 * 128];
    ls[threadIdx.x] = 0.f;
    const int lane = threadIdx.x & 63, wid = threadIdx.x >> 6;
    const int q = lane >> 4, li = lane & 15;
    int tile = blockIdx.x * 4 + wid;
    int rowA = tile * 16 + li;
    unsigned m = pm[rowA];
    const int* ip = idx + (size_t)rowA * 8;
    f32x4 acc[8];
    #pragma unroll
    for (int nb = 0; nb < 8; nb++) acc[nb] = (f32x4)0.f;
    for (int t = 0; t < 8; t++) {
        __syncthreads();
        const int4* s = (const int4*)(Wsh + (size_t)t * (2 * 8 * 64 * 8));
        int4* d = (int4*)Wl;
        for (int i = threadIdx.x; i < 1024; i += 256) d[i] = s[i];
        __syncthreads();
        float4 f0 = {0,0,0,0}, f1 = {0,0,0,0}, f2 = {0,0,0,0}, f3 = {0,0,0,0};
        if ((m >> t) & 1u) {
            const float* base = xin + (size_t)ip[t] * 64;
            const float4* p0 = (const float4*)(base + q * 8);
            f0 = p0[0]; f1 = p0[1];
            const float4* p1 = (const float4*)(base + 32 + q * 8);
            f2 = p1[0]; f3 = p1[1];
        }
        bf16x8 a0 = cvt8(f0, f1), a1 = cvt8(f2, f3);
        #pragma unroll
        for (int nb = 0; nb < 8; nb++) {
            bf16x8 b0 = *(const bf16x8*)&Wl[((0 * 8 + nb) * 64 + lane) * 8];
            acc[nb] = __builtin_amdgcn_mfma_f32_16x16x32_bf16(a0, b0, acc[nb], 0, 0, 0);
            bf16x8 b1 = *(const bf16x8*)&Wl[((1 * 8 + nb) * 64 + lane) * 8];
            acc[nb] = __builtin_amdgcn_mfma_f32_16x16x32_bf16(a1, b1, acc[nb], 0, 0, 0);
        }
    }
    int rowD = tile * 16 + q * 4;
    float sum[8], sq[8];
    #pragma unroll
    for (int nb = 0; nb < 8; nb++) {
        sum[nb] = 0.f; sq[nb] = 0.f;
        #pragma unroll
        for (int r = 0; r < 4; r++) {
            float v = acc[nb][r];
            out[(size_t)(rowD + r) * 128 + nb * 16 + li] = v;
            sum[nb] += v; sq[nb] = fmaf(v, v, sq[nb]);
        }
    }
    #pragma unroll
    for (int nb = 0; nb < 8; nb++) {
        int c = nb * 16 + li;
        atomicAdd(&ls[c], sum[nb]); atomicAdd(&ls[128 + c], sq[nb]);
    }
    __syncthreads();
    if (threadIdx.x < 128) {
        atomicAdd(&st[threadIdx.x], ls[threadIdx.x]);
        atomicAdd(&st[128 + threadIdx.x], ls[128 + threadIdx.x]);
    }
}

// ---------------- conv3: tconv, Cin=128 (KB=4), Cout=64 (NB=4) --------------
// Octant-masked: acc += (A masked to rows with off==o) @ W[o]. B-frags from L2
// (128KB working set). Wave handles 2 row-tiles (32 rows) to halve B traffic.
__global__ __launch_bounds__(256)
void k_conv3(const float* __restrict__ xin, const unsigned short* __restrict__ Wsh,
             const int* __restrict__ par, const int* __restrict__ off,
             float* __restrict__ out, float* __restrict__ st, int M) {
    __shared__ float ls[2 * 64];
    if (threadIdx.x < 128) ls[threadIdx.x] = 0.f;
    __syncthreads();
    const int lane = threadIdx.x & 63, wid = threadIdx.x >> 6;
    const int q = lane >> 4, li = lane & 15;
    int pid = blockIdx.x * 4 + wid;
    float sum[4] = {0, 0, 0, 0}, sq[4] = {0, 0, 0, 0};
    if (pid * 32 < M) {
        int r0 = pid * 32 + li, r1 = r0 + 16;
        int p0 = par[r0], p1 = par[r1];
        int o0 = off[r0], o1 = off[r1];
        bf16x8 A0[4], A1[4];
        #pragma unroll
        for (int kb = 0; kb < 4; kb++) {
            const float4* pa = (const float4*)(xin + (size_t)p0 * 128 + kb * 32 + q * 8);
            A0[kb] = cvt8(pa[0], pa[1]);
            const float4* pb = (const float4*)(xin + (size_t)p1 * 128 + kb * 32 + q * 8);
            A1[kb] = cvt8(pb[0], pb[1]);
        }
        f32x4 acc0[4], acc1[4];
        #pragma unroll
        for (int nb = 0; nb < 4; nb++) { acc0[nb] = (f32x4)0.f; acc1[nb] = (f32x4)0.f; }
        bf16x8 z8 = (bf16x8)(short)0;
        for (int o = 0; o < 8; o++) {
            bool s0 = (o0 == o), s1 = (o1 == o);
            if (__ballot(s0 || s1) == 0ull) continue;   // octant absent in both tiles
            bf16x8 M0[4], M1[4];
            #pragma unroll
            for (int kb = 0; kb < 4; kb++) {
                M0[kb] = s0 ? A0[kb] : z8;
                M1[kb] = s1 ? A1[kb] : z8;
            }
            #pragma unroll
            for (int nb = 0; nb < 4; nb++)
                #pragma unroll
                for (int kb = 0; kb < 4; kb++) {
                    bf16x8 b = *(const bf16x8*)(Wsh + ((((size_t)o * 4 + kb) * 4 + nb) * 64 + lane) * 8);
                    acc0[nb] = __builtin_amdgcn_mfma_f32_16x16x32_bf16(M0[kb], b, acc0[nb], 0, 0, 0);
                    acc1[nb] = __builtin_amdgcn_mfma_f32_16x16x32_bf16(M1[kb], b, acc1[nb], 0, 0, 0);
                }
        }
        int d0 = pid * 32 + q * 4, d1 = d0 + 16;
        #pragma unroll
        for (int nb = 0; nb < 4; nb++)
            #pragma unroll
            for (int r = 0; r < 4; r++) {
                float v0 = acc0[nb][r], v1 = acc1[nb][r];
                out[(size_t)(d0 + r) * 64 + nb * 16 + li] = v0;
                out[(size_t)(d1 + r) * 64 + nb * 16 + li] = v1;
                sum[nb] += v0 + v1;
                sq[nb] = fmaf(v0, v0, sq[nb]); sq[nb] = fmaf(v1, v1, sq[nb]);
            }
    }
    #pragma unroll
    for (int nb = 0; nb < 4; nb++) {
        int c = nb * 16 + li;
        atomicAdd(&ls[c], sum[nb]); atomicAdd(&ls[64 + c], sq[nb]);
    }
    __syncthreads();
    if (threadIdx.x < 64) {
        atomicAdd(&st[threadIdx.x], ls[threadIdx.x]);
        atomicAdd(&st[128 + threadIdx.x], ls[64 + threadIdx.x]);
    }
}

// ---------------- conv4: tconv, Cin=64 (KB=2), Cout=32 (NB=2) ---------------
// All 8 octant weights in LDS (32KB). Wave = 2 row-tiles.
__global__ __launch_bounds__(256)
void k_conv4(const float* __restrict__ xin, const unsigned short* __restrict__ Wsh,
             const int* __restrict__ par, const int* __restrict__ off,
             float* __restrict__ out, float* __restrict__ st, int M) {
    __shared__ unsigned short Wl[8 * 2 * 2 * 64 * 8];   // 32KB
    __shared__ float ls[2 * 32];
    {
        const int4* s = (const int4*)Wsh; int4* d = (int4*)Wl;
        for (int i = threadIdx.x; i < 2048; i += 256) d[i] = s[i];
    }
    if (threadIdx.x < 64) ls[threadIdx.x] = 0.f;
    __syncthreads();
    const int lane = threadIdx.x & 63, wid = threadIdx.x >> 6;
    const int q = lane >> 4, li = lane & 15;
    int pid = blockIdx.x * 4 + wid;
    float sum[2] = {0, 0}, sq[2] = {0, 0};
    if (pid * 32 < M) {
        int r0 = pid * 32 + li, r1 = r0 + 16;
        int p0 = par[r0], p1 = par[r1];
        int o0 = off[r0], o1 = off[r1];
        bf16x8 A0[2], A1[2];
        #pragma unroll
        for (int kb = 0; kb < 2; kb++) {
            const float4* pa = (const float4*)(xin + (size_t)p0 * 64 + kb * 32 + q * 8);
            A0[kb] = cvt8(pa[0], pa[1]);
            const float4* pb = (const float4*)(xin + (size_t)p1 * 64 + kb * 32 + q * 8);
            A1[kb] = cvt8(pb[0], pb[1]);
        }
        f32x4 acc0[2], acc1[2];
        #pragma unroll
        for (int nb = 0; nb < 2; nb++) { acc0[nb] = (f32x4)0.f; acc1[nb] = (f32x4)0.f; }
        bf16x8 z8 = (bf16x8)(short)0;
        for (int o = 0; o < 8; o++) {
            bool s0 = (o0 == o), s1 = (o1 == o);
            if (__ballot(s0 || s1) == 0ull) continue;
            bf16x8 M0[2], M1[2];
            #pragma unroll
            for (int kb = 0; kb < 2; kb++) {
                M0[kb] = s0 ? A0[kb] : z8;
                M1[kb] = s1 ? A1[kb] : z8;
            }
            #pragma unroll
            for (int nb = 0; nb < 2; nb++)
                #pragma unroll
                for (int kb = 0; kb < 2; kb++) {
                    bf16x8 b = *(const bf16x8*)&Wl[(((o * 2 + kb) * 2 + nb) * 64 + lane) * 8];
                    acc0[nb] = __builtin_amdgcn_mfma_f32_16x16x32_bf16(M0[kb], b, acc0[nb], 0, 0, 0);
                    acc1[nb] = __builtin_amdgcn_mfma_f32_16x16x32_bf16(M1[kb], b, acc1[nb], 0, 0, 0);
                }
        }
        int d0 = pid * 32 + q * 4, d1 = d0 + 16;
        #pragma unroll
        for (int nb = 0; nb < 2; nb++)
            #pragma unroll
            for (int r = 0; r < 4; r++) {
                float v0 = acc0[nb][r], v1 = acc1[nb][r];
                out[(size_t)(d0 + r) * 32 + nb * 16 + li] = v0;
                out[(size_t)(d1 + r) * 32 + nb * 16 + li] = v1;
                sum[nb] += v0 + v1;
                sq[nb] = fmaf(v0, v0, sq[nb]); sq[nb] = fmaf(v1, v1, sq[nb]);
            }
    }
    #pragma unroll
    for (int nb = 0; nb < 2; nb++) {
        int c = nb * 16 + li;
        atomicAdd(&ls[c], sum[nb]); atomicAdd(&ls[32 + c], sq[nb]);
    }
    __syncthreads();
    if (threadIdx.x < 32) {
        atomicAdd(&st[threadIdx.x], ls[threadIdx.x]);
        atomicAdd(&st[128 + threadIdx.x], ls[32 + threadIdx.x]);
    }
}

// ---------------- in-place instance norm (unchanged from R1) ----------------
template <int C>
__global__ __launch_bounds__(256)
void k_norm(float* __restrict__ f, int M, const float* __restrict__ st,
            const float* __restrict__ g, const float* __restrict__ b) {
    __shared__ float sc[C], sh[C];
    if (threadIdx.x < C) {
        int c = threadIdx.x;
        float invM = 1.0f / (float)M;
        float mu = st[c] * invM;
        float var = fmaf(st[128 + c], invM, -mu * mu);
        float s = rsqrtf(var + EPS_V) * g[c];
        sc[c] = s;
        sh[c] = fmaf(-mu, s, b[c]);
    }
    __syncthreads();
    const int total = M * (C / 4);
    const int cq = C / 4;
    float4* p = (float4*)f;
    for (int i = blockIdx.x * blockDim.x + threadIdx.x; i < total;
         i += gridDim.x * blockDim.x) {
        float4 v = p[i];
        int c0 = (i % cq) * 4;
        v.x = fmaf(v.x, sc[c0 + 0], sh[c0 + 0]);
        v.y = fmaf(v.y, sc[c0 + 1], sh[c0 + 1]);
        v.z = fmaf(v.z, sc[c0 + 2], sh[c0 + 2]);
        v.w = fmaf(v.w, sc[c0 + 3], sh[c0 + 3]);
        p[i] = v;
    }
}

extern "C" void kernel_launch(void* const* d_in, const int* in_sizes, int n_in,
                              void* d_out, int out_size, void* d_ws, size_t ws_size,
                              hipStream_t stream) {
    const float* x   = (const float*)d_in[0];
    const float* W1  = (const float*)d_in[1];
    const float* W2  = (const float*)d_in[2];
    const float* W3  = (const float*)d_in[3];
    const float* W4  = (const float*)d_in[4];
    const float* g1  = (const float*)d_in[5];
    const float* b1  = (const float*)d_in[6];
    const float* g2  = (const float*)d_in[7];
    const float* b2  = (const float*)d_in[8];
    const float* g3  = (const float*)d_in[9];
    const float* b3  = (const float*)d_in[10];
    const float* g4  = (const float*)d_in[11];
    const float* b4  = (const float*)d_in[12];
    const int*  idx1 = (const int*)d_in[13];
    const void* msk1 = d_in[14];
    const int*  idx2 = (const int*)d_in[15];
    const void* msk2 = d_in[16];
    const int*  par2 = (const int*)d_in[17];
    const int*  off2 = (const int*)d_in[18];
    const int*  par1 = (const int*)d_in[19];
    const int*  off1 = (const int*)d_in[20];

    const int N1 = in_sizes[17];
    const int N0 = in_sizes[19];
    const int N2 = in_sizes[15] / 8;

    float* outp = (float*)d_out;
    float* sA = outp;                          // x_down2 [N0,32]
    float* sB = sA + (size_t)N0 * 32;          // x_down1 [N1,64]
    float* sC = sB + (size_t)N1 * 64;          // x_up2   [N2,128]
    float* sD = sC + (size_t)N2 * 128;         // x_up1   [N1,64]

    // ws layout (16B aligned): flag | stats | wshuf1..4 | pm1 | pm2
    char* w = (char*)d_ws;
    int*   flag = (int*)w;
    float* st   = (float*)(w + 16);            // 1024 floats
    float* st1 = st, *st2 = st + 256, *st3 = st + 512, *st4 = st + 768;
    unsigned short* ws1 = (unsigned short*)(w + 4608);            // 32KB
    unsigned short* ws2 = (unsigned short*)(w + 4608 + 32768);    // 128KB
    unsigned short* ws3 = (unsigned short*)(w + 4608 + 163840);   // 128KB
    unsigned short* ws4 = (unsigned short*)(w + 4608 + 294912);   // 32KB
    unsigned char* pm1 = (unsigned char*)(w + 4608 + 327680);
    unsigned char* pm2 = pm1 + (((size_t)N1 + 255) & ~(size_t)255);

    hipMemsetAsync(d_ws, 0, 4608, stream);

    int nwords = N1 * 8 / 4; if (nwords > 4096) nwords = 4096;
    k_detect<<<1, 256, 0, stream>>>((const unsigned int*)msk1, nwords, flag);
    k_pack<<<(N1 + 255) / 256, 256, 0, stream>>>(msk1, N1, flag, pm1);
    k_pack<<<(N2 + 255) / 256, 256, 0, stream>>>(msk2, N2, flag, pm2);
    k_wshuf<<<8, 256, 0, stream>>>(W1, 8, 32, 64, ws1);
    k_wshuf<<<32, 256, 0, stream>>>(W2, 8, 64, 128, ws2);
    k_wshuf<<<32, 256, 0, stream>>>(W3, 8, 128, 64, ws3);
    k_wshuf<<<8, 256, 0, stream>>>(W4, 8, 64, 32, ws4);

    // layer 1 -> x_up1 (slot D): 12500 tiles, 4/block
    k_conv1<<<3125, 256, 0, stream>>>(x, ws1, idx1, pm1, sD, st1, N1);
    k_norm<64><<<1024, 256, 0, stream>>>(sD, N1, st1, g1, b1);

    // layer 2 -> x_up2 (slot C): 2048 tiles, 4/block
    k_conv2<<<512, 256, 0, stream>>>(sD, ws2, idx2, pm2, sC, st2, N2);
    k_norm<128><<<512, 256, 0, stream>>>(sC, N2, st2, g2, b2);

    // layer 3 -> x_down1 (slot B): 6250 tile-pairs, 4/block
    k_conv3<<<1563, 256, 0, stream>>>(sC, ws3, par2, off2, sB, st3, N1);
    k_norm<64><<<1024, 256, 0, stream>>>(sB, N1, st3, g3, b3);

    // layer 4 -> x_down2 (slot A): 25000 tile-pairs, 4/block
    k_conv4<<<6250, 256, 0, stream>>>(sB, ws4, par1, off1, sA, st4, N0);
    k_norm<32><<<1024, 256, 0, stream>>>(sA, N0, st4, g4, b4);
}